// Round 1
// baseline (117.046 us; speedup 1.0000x reference)
//
#include <hip/hip_runtime.h>
#include <math.h>

// Shapes: B=4, N=8192, F=64; MLP: 67 -> 64 -> 32 -> 1
// d_out: [0,32768) boundary_prob | [32768,+2097152) features | last 4: conf
#define NB 4
#define NPTS 8192
#define OUT_FEAT_OFF 32768
#define OUT_CONF_OFF (32768 + 2097152)

// ---------------------------------------------------------------------------
// block reduce over 256 threads (verified R1/R4 of previous session)
// ---------------------------------------------------------------------------
__device__ __forceinline__ float blockReduceSum256(float v) {
    __shared__ float sred[4];
#pragma unroll
    for (int o = 32; o > 0; o >>= 1) v += __shfl_down(v, o, 64);
    const int w = threadIdx.x >> 6, l = threadIdx.x & 63;
    __syncthreads();
    if (l == 0) sred[w] = v;
    __syncthreads();
    return sred[0] + sred[1] + sred[2] + sred[3];
}

// ---------------------------------------------------------------------------
// Fused kernel: 512 blocks x 256 threads (2 blocks/CU).
// Each block: 64 points. NEW structure: wave q (wave-uniform via
// readfirstlane) computes layer-1 outputs j in [16q,16q+16) for ALL 64
// points (lane = point). Weight addresses are wave-uniform -> s_load into
// SGPRs, v_fmac with SGPR operand: zero LDS traffic for weights (the old
// lane-quarter layout broadcast-read weights from LDS, ~384 ds_read_b128
// per thread -> LDS-return-BW bound). Inputs x[67] staged in LDS once,
// conflict-free pitch-68 rows, 16 ds_read_b128/thread.
// Layer-2 k-reduction is cross-wave via a small LDS partial buffer.
// Last-arriving block per batch (128 blocks/batch) computes the stats.
// ---------------------------------------------------------------------------
__global__ __launch_bounds__(256) void fused_kernel(
    const float* __restrict__ pts,    // (B,N,3)
    const float* __restrict__ feats,  // (B,N,64)
    const int* __restrict__ mask,     // (B,N)
    const float* __restrict__ W1,     // (64,67)
    const float* __restrict__ b1,
    const float* __restrict__ W2,     // (32,64)
    const float* __restrict__ b2,
    const float* __restrict__ W3,     // (1,32)
    const float* __restrict__ b3,
    float* __restrict__ out,
    int* __restrict__ counters,       // 4 ints in ws, pre-zeroed
    float* __restrict__ wsf)          // stats scratch (after counters)
{
    // X-tile: 64 points x pitch 68 floats (272 B, 16B-aligned).
    // b128 read lane i col kc: bank-group = (i + kc) mod 8 -> conflict-free.
    __shared__ float sX[64 * 68];
    // layer-2 partials from waves 1..3: 3 x 64 rows x pitch 36 floats
    // (144 B, 16B-aligned). group = (9r + m) mod 8 = (r + m) mod 8 -> CF.
    __shared__ float sH[3 * 64 * 36];
    __shared__ int sflag;
    __shared__ int cnts[256];

    const int t = threadIdx.x;
    const int ln = t & 63;
    const int q = __builtin_amdgcn_readfirstlane(t >> 6);  // wave id, SGPR

    // ---- stage features: coalesced global read -> passthrough write + LDS
    {
        const float4* fsrc = (const float4*)feats + (size_t)blockIdx.x * 1024;
        float4* fdst = (float4*)(out + OUT_FEAT_OFF) + (size_t)blockIdx.x * 1024;
#pragma unroll
        for (int i = 0; i < 4; ++i) {
            const int e = i * 256 + t;
            const float4 v = fsrc[e];
            fdst[e] = v;
            *(float4*)&sX[(e >> 4) * 68 + (e & 15) * 4] = v;  // 2-way (free)
        }
    }
    __syncthreads();

    const int p = blockIdx.x * 64 + ln;  // lane = point

    // ---- x into registers: 16 conflict-free ds_read_b128 + xyz from global
    float4 xv[16];
#pragma unroll
    for (int kc = 0; kc < 16; ++kc)
        xv[kc] = *(const float4*)&sX[ln * 68 + kc * 4];
    const float px = pts[(size_t)p * 3 + 0];
    const float py = pts[(size_t)p * 3 + 1];
    const float pz = pts[(size_t)p * 3 + 2];

    // ---- layer 1: j in [16q,16q+16), weights via wave-uniform s_load
    const int jq = q * 16;
    float h1[16];
#pragma unroll
    for (int jj = 0; jj < 16; ++jj) {
        const float* wr = W1 + (size_t)(jq + jj) * 67;  // uniform address
        float a = b1[jq + jj];                          // uniform
#pragma unroll
        for (int kc = 0; kc < 16; ++kc) {
            a = fmaf(xv[kc].x, wr[4 * kc + 0], a);
            a = fmaf(xv[kc].y, wr[4 * kc + 1], a);
            a = fmaf(xv[kc].z, wr[4 * kc + 2], a);
            a = fmaf(xv[kc].w, wr[4 * kc + 3], a);
        }
        a = fmaf(px, wr[64], a);
        a = fmaf(py, wr[65], a);
        a = fmaf(pz, wr[66], a);
        h1[jj] = fmaxf(a, 0.f);
    }

    // ---- layer 2 partial: k in [jq, jq+16), all 32 outputs (rows contiguous
    //      16-float chunks -> s_load_dwordx16 per row)
    float p2[32];
#pragma unroll
    for (int j = 0; j < 32; ++j) {
        const float* wr = W2 + (size_t)j * 64 + jq;  // uniform address
        float a = 0.f;
#pragma unroll
        for (int kk = 0; kk < 16; ++kk) a = fmaf(h1[kk], wr[kk], a);
        p2[j] = a;
    }

    // ---- cross-wave reduce: waves 1..3 park partials in LDS, wave 0 sums
    if (q != 0) {
        float* dst = &sH[(size_t)((q - 1) * 64 + ln) * 36];
#pragma unroll
        for (int m = 0; m < 8; ++m) {
            float4 v;
            v.x = p2[4 * m + 0]; v.y = p2[4 * m + 1];
            v.z = p2[4 * m + 2]; v.w = p2[4 * m + 3];
            *(float4*)&dst[4 * m] = v;  // conflict-free
        }
    }
    __syncthreads();

    if (q == 0) {
#pragma unroll
        for (int qq = 0; qq < 3; ++qq) {
            const float* src = &sH[(size_t)(qq * 64 + ln) * 36];
#pragma unroll
            for (int m = 0; m < 8; ++m) {
                const float4 v = *(const float4*)&src[4 * m];
                p2[4 * m + 0] += v.x; p2[4 * m + 1] += v.y;
                p2[4 * m + 2] += v.z; p2[4 * m + 3] += v.w;
            }
        }
        // ---- bias + ReLU + layer 3 + sigmoid + mask (wave 0, lane = point)
        float z = b3[0];
#pragma unroll
        for (int j = 0; j < 32; ++j)
            z = fmaf(fmaxf(p2[j] + b2[j], 0.f), W3[j], z);  // W3 uniform
        float sc = 1.0f / (1.0f + expf(-z));
        if (mask[p] == 0) sc = 0.0f;
        out[p] = sc;  // coalesced 64-lane dword store
    }

    // ---- arrival: last of 128 blocks of this batch does the stats
    const int batch = blockIdx.x >> 7;
    __syncthreads();  // drains stores (vmcnt(0) before s_barrier)
    if (t == 0) {
        const int old = __hip_atomic_fetch_add(&counters[batch], 1,
                                               __ATOMIC_ACQ_REL,
                                               __HIP_MEMORY_SCOPE_AGENT);
        sflag = (old == 127);
    }
    __syncthreads();
    if (!sflag) return;
    __builtin_amdgcn_fence(__ATOMIC_ACQUIRE, "agent");  // device-scope acquire

    // ================= stats for `batch` (256 threads, 32 pts/thread) ======
    float* scores = out + (size_t)batch * NPTS;
    const float* P = pts + (size_t)batch * NPTS * 3;
    const int* M = mask + (size_t)batch * NPTS;
    float* g = wsf + (size_t)batch * 40960;   // compacted xyz
    float* dd = g + 3 * NPTS;                 // pair distances

    // load 32 contiguous scores + build mask bitfield (order-preserving)
    float s[32];
    unsigned int mbits = 0;
#pragma unroll
    for (int i = 0; i < 8; ++i) {
        const float4 s4 = ((const float4*)scores)[t * 8 + i];
        s[4*i+0] = s4.x; s[4*i+1] = s4.y; s[4*i+2] = s4.z; s[4*i+3] = s4.w;
        const int4 m4 = ((const int4*)M)[t * 8 + i];
        mbits |= (m4.x != 0 ? 1u : 0u) << (4*i+0);
        mbits |= (m4.y != 0 ? 1u : 0u) << (4*i+1);
        mbits |= (m4.z != 0 ? 1u : 0u) << (4*i+2);
        mbits |= (m4.w != 0 ? 1u : 0u) << (4*i+3);
    }

    float ss = 0.f;
#pragma unroll
    for (int i = 0; i < 32; ++i) ss += s[i];  // scores already masked
    const float nleaf = blockReduceSum256((float)__popc(mbits));
    const float ssum = blockReduceSum256(ss);

    if (nleaf < 10.0f) {
        const float4 z4 = {0.f, 0.f, 0.f, 0.f};
#pragma unroll
        for (int i = 0; i < 8; ++i) ((float4*)scores)[t * 8 + i] = z4;
        if (t == 0) out[OUT_CONF_OFF + batch] = 0.0f;
        return;
    }

    // clarity
    const float mean = ssum / fmaxf(nleaf, 1.0f);
    float vs = 0.f;
#pragma unroll
    for (int i = 0; i < 32; ++i) {
        if (mbits & (1u << i)) {
            const float d0 = s[i] - mean;
            vs += d0 * d0;
        }
    }
    const float clarity = blockReduceSum256(vs) / fmaxf(nleaf - 1.0f, 1.0f);

    // order-preserving compaction of score > 0.7 points
    int c0 = 0;
#pragma unroll
    for (int i = 0; i < 32; ++i) c0 += (s[i] > 0.7f);
    cnts[t] = c0;
    __syncthreads();
    for (int off = 1; off < 256; off <<= 1) {  // Hillis-Steele inclusive scan
        const int v = cnts[t];
        const int a = (t >= off) ? cnts[t - off] : 0;
        __syncthreads();
        cnts[t] = v + a;
        __syncthreads();
    }
    const int cnt = cnts[255];
    int pos = cnts[t] - c0;  // exclusive prefix
#pragma unroll
    for (int i = 0; i < 32; ++i) {
        if (s[i] > 0.7f) {
            const int idx = t * 32 + i;
            g[3 * pos + 0] = P[3 * idx + 0];
            g[3 * pos + 1] = P[3 * idx + 1];
            g[3 * pos + 2] = P[3 * idx + 2];
            ++pos;
        }
    }
    __syncthreads();

    // consecutive distances among first cnt selected points
    const int npair = cnt - 1;
    float dsum = 0.f;
    for (int i = t; i < npair; i += 256) {
        const float ax = g[3 * i + 0] - g[3 * i + 3];
        const float ay = g[3 * i + 1] - g[3 * i + 4];
        const float az = g[3 * i + 2] - g[3 * i + 5];
        const float d0 = sqrtf(ax * ax + ay * ay + az * az);
        dd[i] = d0;
        dsum += d0;
    }
    const float dtot = blockReduceSum256(dsum);
    const float npf = (float)npair;
    const float dmean = dtot / fmaxf(npf, 1.0f);
    float dv = 0.f;
    for (int i = t; i < npair; i += 256) {
        const float e = dd[i] - dmean;
        dv += e * e;
    }
    const float dvar = blockReduceSum256(dv) / fmaxf(npf - 1.0f, 1.0f);

    float cont = fminf(fmaxf(1.0f / (dvar + 1e-8f), 0.0f), 1.0f);
    if (!(cnt > 5)) cont = 0.0f;
    const float conf = fminf(fmaxf(clarity * cont, 0.0f), 1.0f);
    if (t == 0) out[OUT_CONF_OFF + batch] = conf;
}

// ---------------------------------------------------------------------------
extern "C" void kernel_launch(void* const* d_in, const int* in_sizes, int n_in,
                              void* d_out, int out_size, void* d_ws, size_t ws_size,
                              hipStream_t stream) {
    const float* points   = (const float*)d_in[0];
    const float* features = (const float*)d_in[1];
    const int*   leafmask = (const int*)d_in[2];
    const float* W1 = (const float*)d_in[3];
    const float* b1 = (const float*)d_in[4];
    const float* W2 = (const float*)d_in[5];
    const float* b2 = (const float*)d_in[6];
    const float* W3 = (const float*)d_in[7];
    const float* b3 = (const float*)d_in[8];
    float* out = (float*)d_out;
    int* counters = (int*)d_ws;
    float* wsf = (float*)d_ws + 64;  // stats scratch after counters

    (void)hipMemsetAsync(d_ws, 0, 64, stream);  // zero the 4 arrival counters
    fused_kernel<<<512, 256, 0, stream>>>(
        points, features, leafmask, W1, b1, W2, b2, W3, b3, out, counters, wsf);
}

// Round 2
// 109.636 us; speedup vs baseline: 1.0676x; 1.0676x over previous
//
#include <hip/hip_runtime.h>
#include <math.h>

// Shapes: B=4, N=8192, F=64; MLP: 67 -> 64 -> 32 -> 1
// d_out: [0,32768) boundary_prob | [32768,+2097152) features | last 4: conf
#define NB 4
#define NPTS 8192
#define OUT_FEAT_OFF 32768
#define OUT_CONF_OFF (32768 + 2097152)

// ---------------------------------------------------------------------------
// block reduce over 256 threads
// ---------------------------------------------------------------------------
__device__ __forceinline__ float blockReduceSum256(float v) {
    __shared__ float sred[4];
#pragma unroll
    for (int o = 32; o > 0; o >>= 1) v += __shfl_down(v, o, 64);
    const int w = threadIdx.x >> 6, l = threadIdx.x & 63;
    __syncthreads();
    if (l == 0) sred[w] = v;
    __syncthreads();
    return sred[0] + sred[1] + sred[2] + sred[3];
}

// ---------------------------------------------------------------------------
// Fused kernel: 512 blocks x 256 threads (2 blocks/CU, 2 waves/SIMD).
// Block = 64 points, lane = point. Wave q computes layer-1 j in [16q,16q+16)
// for all 64 points; weights come in via wave-uniform s_load (SGPR operand,
// zero LDS traffic). __launch_bounds__(256,2) raises the VGPR cap to 256 so
// xv[16] (64 VGPRs) stays resident and the compiler can pipeline the s_loads
// across the fully-unrolled jj loop (round-1 failure: VGPR=68 -> no
// pipelining, serial 268-cycle chains exposed). Dot products split into
// 4 / 2 independent accumulators to cut dependent-FMA latency below issue
// cost. Layer-2 k-reduction crosses waves via a small LDS partial buffer.
// Last-arriving block per batch (128 blocks/batch) computes the stats:
// wave-shfl scan (2 barriers), dd in LDS (aliases dead sX/sH), unrolled
// distance passes.
// ---------------------------------------------------------------------------
__global__ __launch_bounds__(256, 2) void fused_kernel(
    const float* __restrict__ pts,    // (B,N,3)
    const float* __restrict__ feats,  // (B,N,64)
    const int* __restrict__ mask,     // (B,N)
    const float* __restrict__ W1,     // (64,67)
    const float* __restrict__ b1,
    const float* __restrict__ W2,     // (32,64)
    const float* __restrict__ b2,
    const float* __restrict__ W3,     // (1,32)
    const float* __restrict__ b3,
    float* __restrict__ out,
    int* __restrict__ counters,       // 4 ints in ws, pre-zeroed
    float* __restrict__ wsf)          // stats scratch (after counters)
{
    // Single LDS pool, aliased across phases:
    //  MLP phase : sX = smem[0 .. 4352)  (64 rows x pitch 68, conflict-free)
    //              sH = smem[4352 .. 11264)  (3*64 rows x pitch 36, CF)
    //  stats     : dd = smem[0 .. 8191)  (pair distances; sX/sH are dead)
    __shared__ float smem[11264];
    float* const sX = smem;
    float* const sH = smem + 64 * 68;
    __shared__ int sflag;
    __shared__ int swt[4];

    const int t = threadIdx.x;
    const int ln = t & 63;
    const int q = __builtin_amdgcn_readfirstlane(t >> 6);  // wave id, SGPR

    const int p = blockIdx.x * 64 + ln;  // lane = point

    // ---- issue xyz loads early (overlap with staging latency)
    const float px = pts[(size_t)p * 3 + 0];
    const float py = pts[(size_t)p * 3 + 1];
    const float pz = pts[(size_t)p * 3 + 2];

    // ---- stage features: coalesced global read -> passthrough write + LDS
    {
        const float4* fsrc = (const float4*)feats + (size_t)blockIdx.x * 1024;
        float4* fdst = (float4*)(out + OUT_FEAT_OFF) + (size_t)blockIdx.x * 1024;
#pragma unroll
        for (int i = 0; i < 4; ++i) {
            const int e = i * 256 + t;
            const float4 v = fsrc[e];
            fdst[e] = v;
            *(float4*)&sX[(e >> 4) * 68 + (e & 15) * 4] = v;  // 2-way (free)
        }
    }
    __syncthreads();

    // ---- x into registers: 16 conflict-free ds_read_b128
    float4 xv[16];
#pragma unroll
    for (int kc = 0; kc < 16; ++kc)
        xv[kc] = *(const float4*)&sX[ln * 68 + kc * 4];

    // ---- layer 1: j in [16q,16q+16), weights via wave-uniform s_load.
    //      4 independent accumulators: dep chain 64 cy < issue 134 cy.
    const int jq = q * 16;
    float h1[16];
#pragma unroll
    for (int jj = 0; jj < 16; ++jj) {
        const float* __restrict__ wr = W1 + (size_t)(jq + jj) * 67;  // uniform
        float a0 = b1[jq + jj], a1 = 0.f, a2 = 0.f, a3 = 0.f;
#pragma unroll
        for (int kc = 0; kc < 16; ++kc) {
            a0 = fmaf(xv[kc].x, wr[4 * kc + 0], a0);
            a1 = fmaf(xv[kc].y, wr[4 * kc + 1], a1);
            a2 = fmaf(xv[kc].z, wr[4 * kc + 2], a2);
            a3 = fmaf(xv[kc].w, wr[4 * kc + 3], a3);
        }
        a0 = fmaf(px, wr[64], a0);
        a1 = fmaf(py, wr[65], a1);
        a2 = fmaf(pz, wr[66], a2);
        h1[jj] = fmaxf((a0 + a1) + (a2 + a3), 0.f);
    }

    // ---- layer 2 partial: k in [jq, jq+16), all 32 outputs (2 accumulators)
    float p2[32];
#pragma unroll
    for (int j = 0; j < 32; ++j) {
        const float* __restrict__ wr = W2 + (size_t)j * 64 + jq;  // uniform
        float a0 = 0.f, a1 = 0.f;
#pragma unroll
        for (int kk = 0; kk < 8; ++kk) {
            a0 = fmaf(h1[2 * kk + 0], wr[2 * kk + 0], a0);
            a1 = fmaf(h1[2 * kk + 1], wr[2 * kk + 1], a1);
        }
        p2[j] = a0 + a1;
    }

    // ---- cross-wave reduce: waves 1..3 park partials in LDS, wave 0 sums
    if (q != 0) {
        float* dst = &sH[(size_t)((q - 1) * 64 + ln) * 36];
#pragma unroll
        for (int m = 0; m < 8; ++m) {
            float4 v;
            v.x = p2[4 * m + 0]; v.y = p2[4 * m + 1];
            v.z = p2[4 * m + 2]; v.w = p2[4 * m + 3];
            *(float4*)&dst[4 * m] = v;  // conflict-free (pitch 36)
        }
    }
    __syncthreads();

    if (q == 0) {
#pragma unroll
        for (int qq = 0; qq < 3; ++qq) {
            const float* src = &sH[(size_t)(qq * 64 + ln) * 36];
#pragma unroll
            for (int m = 0; m < 8; ++m) {
                const float4 v = *(const float4*)&src[4 * m];
                p2[4 * m + 0] += v.x; p2[4 * m + 1] += v.y;
                p2[4 * m + 2] += v.z; p2[4 * m + 3] += v.w;
            }
        }
        // ---- bias + ReLU + layer 3 + sigmoid + mask (wave 0, lane = point)
        float z = b3[0];
#pragma unroll
        for (int j = 0; j < 32; ++j)
            z = fmaf(fmaxf(p2[j] + b2[j], 0.f), W3[j], z);  // W3 uniform
        float sc = 1.0f / (1.0f + expf(-z));
        if (mask[p] == 0) sc = 0.0f;
        out[p] = sc;  // coalesced 64-lane dword store
    }

    // ---- arrival: last of 128 blocks of this batch does the stats
    const int batch = blockIdx.x >> 7;
    __syncthreads();  // drains stores (vmcnt(0) before s_barrier)
    if (t == 0) {
        const int old = __hip_atomic_fetch_add(&counters[batch], 1,
                                               __ATOMIC_ACQ_REL,
                                               __HIP_MEMORY_SCOPE_AGENT);
        sflag = (old == 127);
    }
    __syncthreads();
    if (!sflag) return;
    __builtin_amdgcn_fence(__ATOMIC_ACQUIRE, "agent");  // device-scope acquire

    // ================= stats for `batch` (256 threads, 32 pts/thread) ======
    float* scores = out + (size_t)batch * NPTS;
    const float* P = pts + (size_t)batch * NPTS * 3;
    const int* M = mask + (size_t)batch * NPTS;
    float* g = wsf + (size_t)batch * 40960;   // compacted xyz (global)

    // load 32 contiguous scores + build mask bitfield (order-preserving)
    float s[32];
    unsigned int mbits = 0;
#pragma unroll
    for (int i = 0; i < 8; ++i) {
        const float4 s4 = ((const float4*)scores)[t * 8 + i];
        s[4*i+0] = s4.x; s[4*i+1] = s4.y; s[4*i+2] = s4.z; s[4*i+3] = s4.w;
        const int4 m4 = ((const int4*)M)[t * 8 + i];
        mbits |= (m4.x != 0 ? 1u : 0u) << (4*i+0);
        mbits |= (m4.y != 0 ? 1u : 0u) << (4*i+1);
        mbits |= (m4.z != 0 ? 1u : 0u) << (4*i+2);
        mbits |= (m4.w != 0 ? 1u : 0u) << (4*i+3);
    }

    float ss = 0.f;
#pragma unroll
    for (int i = 0; i < 32; ++i) ss += s[i];  // scores already masked
    const float nleaf = blockReduceSum256((float)__popc(mbits));
    const float ssum = blockReduceSum256(ss);

    if (nleaf < 10.0f) {
        const float4 z4 = {0.f, 0.f, 0.f, 0.f};
#pragma unroll
        for (int i = 0; i < 8; ++i) ((float4*)scores)[t * 8 + i] = z4;
        if (t == 0) out[OUT_CONF_OFF + batch] = 0.0f;
        return;
    }

    // clarity (two-pass, same accumulation order as verified version)
    const float mean = ssum / fmaxf(nleaf, 1.0f);
    float vs = 0.f;
#pragma unroll
    for (int i = 0; i < 32; ++i) {
        if (mbits & (1u << i)) {
            const float d0 = s[i] - mean;
            vs += d0 * d0;
        }
    }
    const float clarity = blockReduceSum256(vs) / fmaxf(nleaf - 1.0f, 1.0f);

    // order-preserving compaction of score > 0.7 points.
    // Wave-level inclusive shfl scan + 4 wave totals: 2 barriers (was 16).
    int c0 = 0;
#pragma unroll
    for (int i = 0; i < 32; ++i) c0 += (s[i] > 0.7f);
    int incl = c0;
#pragma unroll
    for (int o = 1; o < 64; o <<= 1) {
        const int u = __shfl_up(incl, o, 64);
        if (ln >= o) incl += u;
    }
    const int w = t >> 6;
    if (ln == 63) swt[w] = incl;
    __syncthreads();
    int woff = 0, cnt = 0;
#pragma unroll
    for (int i = 0; i < 4; ++i) {
        const int wv = swt[i];
        if (i < w) woff += wv;
        cnt += wv;
    }
    int pos = woff + (incl - c0);  // exclusive prefix over thread order
#pragma unroll
    for (int i = 0; i < 32; ++i) {
        if (s[i] > 0.7f) {
            const int idx = t * 32 + i;
            g[3 * pos + 0] = P[3 * idx + 0];
            g[3 * pos + 1] = P[3 * idx + 1];
            g[3 * pos + 2] = P[3 * idx + 2];
            ++pos;
        }
    }
    __syncthreads();  // g visible; sX/sH dead -> smem becomes dd

    // consecutive distances among first cnt selected points.
    // dd lives in LDS now (npair <= 8191 < 11264); unroll-4 batches the
    // independent g loads so latency overlaps.
    float* const ddl = smem;
    const int npair = cnt - 1;
    float dsum = 0.f;
#pragma unroll 4
    for (int i = t; i < npair; i += 256) {
        const float ax = g[3 * i + 0] - g[3 * i + 3];
        const float ay = g[3 * i + 1] - g[3 * i + 4];
        const float az = g[3 * i + 2] - g[3 * i + 5];
        const float d0 = sqrtf(ax * ax + ay * ay + az * az);
        ddl[i] = d0;
        dsum += d0;
    }
    const float dtot = blockReduceSum256(dsum);
    const float npf = (float)npair;
    const float dmean = dtot / fmaxf(npf, 1.0f);
    float dv = 0.f;
#pragma unroll 4
    for (int i = t; i < npair; i += 256) {
        const float e = ddl[i] - dmean;
        dv += e * e;
    }
    const float dvar = blockReduceSum256(dv) / fmaxf(npf - 1.0f, 1.0f);

    float cont = fminf(fmaxf(1.0f / (dvar + 1e-8f), 0.0f), 1.0f);
    if (!(cnt > 5)) cont = 0.0f;
    const float conf = fminf(fmaxf(clarity * cont, 0.0f), 1.0f);
    if (t == 0) out[OUT_CONF_OFF + batch] = conf;
}

// ---------------------------------------------------------------------------
extern "C" void kernel_launch(void* const* d_in, const int* in_sizes, int n_in,
                              void* d_out, int out_size, void* d_ws, size_t ws_size,
                              hipStream_t stream) {
    const float* points   = (const float*)d_in[0];
    const float* features = (const float*)d_in[1];
    const int*   leafmask = (const int*)d_in[2];
    const float* W1 = (const float*)d_in[3];
    const float* b1 = (const float*)d_in[4];
    const float* W2 = (const float*)d_in[5];
    const float* b2 = (const float*)d_in[6];
    const float* W3 = (const float*)d_in[7];
    const float* b3 = (const float*)d_in[8];
    float* out = (float*)d_out;
    int* counters = (int*)d_ws;
    float* wsf = (float*)d_ws + 64;  // stats scratch after counters

    (void)hipMemsetAsync(d_ws, 0, 64, stream);  // zero the 4 arrival counters
    fused_kernel<<<512, 256, 0, stream>>>(
        points, features, leafmask, W1, b1, W2, b2, W3, b3, out, counters, wsf);
}